// Round 1
// baseline (2739.612 us; speedup 1.0000x reference)
//
#include <hip/hip_runtime.h>
#include <math.h>

// ---------------------------------------------------------------------------
// DFNPureModel: fp32 correctness-first baseline.
// Pipeline:
//   h1 = gelu(x@W1+b1)            32768x512
//   df = gelu(h1@W2+b2)           32768x512
//   coords = df@Wc+bc             32768x2
//   h3 = gelu(df@We1[2:] + coords@We1[:2] + be1)   32768x512
//   ef = h3@We2+be2               32768x1027
//   imp = ||ef||, topk 512/4096 per batch (set only - sum over n is
//   permutation invariant), gather pos/states
//   h4 = gelu(states@Wo1+bo1)     4096x2048
//   proj = h4@Wo2+bo2             4096x512
//   out[b,g,:] = (sum_n w(g,n) proj[n,:]) / (sum_n w(g,n) + 1e-8),
//     w = exp(-(g2+p2-2 g.p)/0.1)  -- fused, attn never materialized.
// ---------------------------------------------------------------------------

#define BM 64
#define BN 64
#define BK 16

__device__ __forceinline__ float gelu_exact(float x) {
    return 0.5f * x * (1.0f + erff(x * 0.7071067811865476f));
}

template<bool GELU, bool RANK2>
__global__ __launch_bounds__(256) void gemm_f32(
    const float* __restrict__ A, int lda,
    const float* __restrict__ W, int ldw,
    const float* __restrict__ bias,
    float* __restrict__ C, int ldc,
    int M, int N, int K,
    const float* __restrict__ A2, const float* __restrict__ W2r, int ldw2)
{
    __shared__ float As[BK][BM + 4];
    __shared__ float Bs[BK][BN];
    const int rowStart = blockIdx.y * BM;
    const int colStart = blockIdx.x * BN;
    const int t  = threadIdx.x;
    const int ty = t >> 4, tx = t & 15;
    const int arow = t >> 2, acol = (t & 3) * 4;   // A tile loader: 64x16
    const int brow = t >> 4, bcol = (t & 15) * 4;  // B tile loader: 16x64
    float acc[4][4] = {};

    for (int k0 = 0; k0 < K; k0 += BK) {
        // ---- stage A tile (rows rowStart..+64, k k0..+16); lda multiple of 4
        const float* ap = A + (size_t)(rowStart + arow) * lda + (k0 + acol);
        float4 av = *(const float4*)ap;
        As[acol + 0][arow] = av.x;
        As[acol + 1][arow] = av.y;
        As[acol + 2][arow] = av.z;
        As[acol + 3][arow] = av.w;
        // ---- stage B tile (k k0..+16, cols colStart..+64), N-bounds + odd ldw
        const int c = colStart + bcol;
        const float* wp = W + (size_t)(k0 + brow) * ldw + c;
        float4 bv;
        if (c + 3 < N) {
            if ((((uintptr_t)wp) & 15) == 0) {
                bv = *(const float4*)wp;
            } else {
                bv.x = wp[0]; bv.y = wp[1]; bv.z = wp[2]; bv.w = wp[3];
            }
        } else {
            bv.x = (c + 0 < N) ? wp[0] : 0.f;
            bv.y = (c + 1 < N) ? wp[1] : 0.f;
            bv.z = (c + 2 < N) ? wp[2] : 0.f;
            bv.w = (c + 3 < N) ? wp[3] : 0.f;
        }
        Bs[brow][bcol + 0] = bv.x;
        Bs[brow][bcol + 1] = bv.y;
        Bs[brow][bcol + 2] = bv.z;
        Bs[brow][bcol + 3] = bv.w;
        __syncthreads();
        #pragma unroll
        for (int k = 0; k < BK; k++) {
            float4 a = *(const float4*)&As[k][ty * 4];
            float4 b = *(const float4*)&Bs[k][tx * 4];
            float ar[4] = {a.x, a.y, a.z, a.w};
            float br[4] = {b.x, b.y, b.z, b.w};
            #pragma unroll
            for (int i = 0; i < 4; i++)
                #pragma unroll
                for (int j = 0; j < 4; j++)
                    acc[i][j] += ar[i] * br[j];
        }
        __syncthreads();
    }
    // ---- epilogue: bias (+ rank-2 coords term) (+ gelu), N-bounded store
    #pragma unroll
    for (int i = 0; i < 4; i++) {
        const int row = rowStart + ty * 4 + i;
        float a20 = 0.f, a21 = 0.f;
        if (RANK2) { a20 = A2[(size_t)row * 2]; a21 = A2[(size_t)row * 2 + 1]; }
        #pragma unroll
        for (int j = 0; j < 4; j++) {
            const int col = colStart + tx * 4 + j;
            if (col < N) {
                float v = acc[i][j] + bias[col];
                if (RANK2) v += a20 * W2r[col] + a21 * W2r[ldw2 + col];
                if (GELU) v = gelu_exact(v);
                C[(size_t)row * ldc + col] = v;
            }
        }
    }
}

// coords = df@Wc + bc : one wave per row
__global__ __launch_bounds__(256) void coords_kernel(
    const float* __restrict__ DF, const float* __restrict__ Wc,
    const float* __restrict__ bc, float* __restrict__ CRD)
{
    const int gid  = blockIdx.x * 256 + threadIdx.x;
    const int row  = gid >> 6;
    const int lane = gid & 63;
    const float* d = DF + (size_t)row * 512;
    float s0 = 0.f, s1 = 0.f;
    for (int k = lane; k < 512; k += 64) {
        const float v = d[k];
        const float2 wc = ((const float2*)Wc)[k];
        s0 += v * wc.x;
        s1 += v * wc.y;
    }
    #pragma unroll
    for (int off = 32; off; off >>= 1) {
        s0 += __shfl_down(s0, off);
        s1 += __shfl_down(s1, off);
    }
    if (lane == 0) {
        CRD[(size_t)row * 2 + 0] = s0 + bc[0];
        CRD[(size_t)row * 2 + 1] = s1 + bc[1];
    }
}

// importance = ||ef|| over 1027 dims : one wave per row
__global__ __launch_bounds__(256) void importance_kernel(
    const float* __restrict__ EF, float* __restrict__ IMP)
{
    const int gid  = blockIdx.x * 256 + threadIdx.x;
    const int row  = gid >> 6;
    const int lane = gid & 63;
    const float* e = EF + (size_t)row * 1027;
    float ss = 0.f;
    for (int k = lane; k < 1027; k += 64) { const float v = e[k]; ss += v * v; }
    #pragma unroll
    for (int off = 32; off; off >>= 1) ss += __shfl_down(ss, off);
    if (lane == 0) IMP[row] = sqrtf(ss);
}

// per-batch top-512 of 4096 via LDS bitonic sort (desc value, asc index ties)
__global__ __launch_bounds__(1024) void topk_kernel(
    const float* __restrict__ IMP, int* __restrict__ IDX)
{
    __shared__ float v[4096];
    __shared__ int   ix[4096];
    const int b = blockIdx.x, t = threadIdx.x;
    for (int i = t; i < 4096; i += 1024) { v[i] = IMP[b * 4096 + i]; ix[i] = i; }
    __syncthreads();
    for (int k = 2; k <= 4096; k <<= 1) {
        for (int j = k >> 1; j > 0; j >>= 1) {
            for (int q = 0; q < 4; q++) {
                const int i = t + (q << 10);
                const int l = i ^ j;
                if (l > i) {
                    const float vi = v[i], vl = v[l];
                    const int   ii = ix[i], il = ix[l];
                    // strict total order: i belongs after l in (desc, idx-asc)
                    const bool after = (vi < vl) || (vi == vl && ii > il);
                    const bool dirAsc = ((i & k) == 0);
                    if (dirAsc ? after : !after) {
                        v[i] = vl; v[l] = vi; ix[i] = il; ix[l] = ii;
                    }
                }
            }
            __syncthreads();
        }
    }
    if (t < 512) IDX[b * 512 + t] = ix[t];
}

// gather positions (first 2) and states (next 1024) of selected rows
__global__ __launch_bounds__(256) void gather_kernel(
    const float* __restrict__ EF, const int* __restrict__ IDX,
    float* __restrict__ POS, float* __restrict__ ST)
{
    const int bn  = blockIdx.x;        // b*512+n
    const int b   = bn >> 9;
    const int row = IDX[bn];
    const float* src = EF + ((size_t)(b * 4096) + row) * 1027;
    const int t = threadIdx.x;
    if (t < 2) POS[(size_t)bn * 2 + t] = src[t];
    float* dst = ST + (size_t)bn * 1024;
    for (int k = t; k < 1024; k += 256) dst[k] = src[2 + k];
}

// fused: w = exp(-(g2+p2-2 g.p)*10), out = (w @ proj) / (rowsum(w)+1e-8)
// block = 64 g-points x 128 d-cols, loop n in tiles of 32
__global__ __launch_bounds__(256) void attn_out_kernel(
    const float* __restrict__ POS,   // [8][512][2]
    const float* __restrict__ PROJ,  // [8][512][512]
    float* __restrict__ OUT)         // [8][10000][512]
{
    const int GT = 64, NT = 32, DT = 128;
    __shared__ float pj[NT][DT];
    __shared__ float wt[GT][NT + 1];
    __shared__ float ppos[NT][2];
    __shared__ float srow[GT];
    const int b  = blockIdx.z;
    const int g0 = blockIdx.x * GT;
    const int d0 = blockIdx.y * DT;
    const int t  = threadIdx.x;
    // w-phase mapping: row glw, 8 consecutive n
    const int glw = t >> 2, nw0 = (t & 3) * 8;
    const int gw = g0 + glw;
    const bool gvalid = gw < 10000;
    const float step = 2.0f / 99.0f;
    const int gi = gw / 100, gj = gw - gi * 100;
    const float gx = -1.f + step * (float)gi;
    const float gy = -1.f + step * (float)gj;
    const float g2 = gx * gx + gy * gy;
    // acc mapping: 4 g-rows x 8 d-cols
    const int rowgrp = t >> 4, colgrp = t & 15;
    float acc[4][8] = {};
    float wsum = 0.f;

    for (int n0 = 0; n0 < 512; n0 += NT) {
        { // stage proj tile 32x128 (each thread 16 consecutive floats)
            const float* pp = PROJ + ((size_t)(b * 512 + n0 + (t >> 3))) * 512
                              + d0 + (t & 7) * 16;
            float* dst = &pj[t >> 3][(t & 7) * 16];
            ((float4*)dst)[0] = ((const float4*)pp)[0];
            ((float4*)dst)[1] = ((const float4*)pp)[1];
            ((float4*)dst)[2] = ((const float4*)pp)[2];
            ((float4*)dst)[3] = ((const float4*)pp)[3];
        }
        if (t < 64)
            ppos[t >> 1][t & 1] = POS[((size_t)b * 512 + n0 + (t >> 1)) * 2 + (t & 1)];
        __syncthreads();
        // compute w tile 64x32
        #pragma unroll
        for (int r = 0; r < 8; r++) {
            const int nl = nw0 + r;
            const float px = ppos[nl][0], py = ppos[nl][1];
            const float sq = g2 + px * px + py * py - 2.f * (gx * px + gy * py);
            const float w = gvalid ? expf(-sq * 10.0f) : 0.f;
            wt[glw][nl] = w;
            wsum += w;
        }
        __syncthreads();
        // accumulate
        for (int nl = 0; nl < NT; nl++) {
            float wr[4];
            #pragma unroll
            for (int i = 0; i < 4; i++) wr[i] = wt[rowgrp * 4 + i][nl];
            const float4 p0 = *(const float4*)&pj[nl][colgrp * 8];
            const float4 p1 = *(const float4*)&pj[nl][colgrp * 8 + 4];
            const float pv[8] = {p0.x, p0.y, p0.z, p0.w, p1.x, p1.y, p1.z, p1.w};
            #pragma unroll
            for (int i = 0; i < 4; i++)
                #pragma unroll
                for (int j = 0; j < 8; j++)
                    acc[i][j] += wr[i] * pv[j];
        }
        __syncthreads();
    }
    // rowsum: reduce 4 lanes (same glw) -> srow
    wsum += __shfl_down(wsum, 2, 4);
    wsum += __shfl_down(wsum, 1, 4);
    if ((t & 3) == 0) srow[glw] = wsum;
    __syncthreads();
    #pragma unroll
    for (int i = 0; i < 4; i++) {
        const int g = g0 + rowgrp * 4 + i;
        if (g < 10000) {
            const float inv = 1.0f / (srow[rowgrp * 4 + i] + 1e-8f);
            float* op = OUT + ((size_t)b * 10000 + g) * 512 + d0 + colgrp * 8;
            #pragma unroll
            for (int j = 0; j < 8; j++) op[j] = acc[i][j] * inv;
        }
    }
}

extern "C" void kernel_launch(void* const* d_in, const int* in_sizes, int n_in,
                              void* d_out, int out_size, void* d_ws, size_t ws_size,
                              hipStream_t stream)
{
    const float* x   = (const float*)d_in[0];
    const float* W1  = (const float*)d_in[1];
    const float* b1  = (const float*)d_in[2];
    const float* W2  = (const float*)d_in[3];
    const float* b2  = (const float*)d_in[4];
    const float* Wc  = (const float*)d_in[5];
    const float* bc  = (const float*)d_in[6];
    const float* We1 = (const float*)d_in[7];
    const float* be1 = (const float*)d_in[8];
    const float* We2 = (const float*)d_in[9];
    const float* be2 = (const float*)d_in[10];
    const float* Wo1 = (const float*)d_in[11];
    const float* bo1 = (const float*)d_in[12];
    const float* Wo2 = (const float*)d_in[13];
    const float* bo2 = (const float*)d_in[14];
    float* out = (float*)d_out;

    const int BS = 32768;  // 8*4096 rows
    // workspace layout (~278 MB total)
    float* bufA = (float*)d_ws;                  // 32768x512
    float* bufB = bufA + (size_t)BS * 512;       // 32768x512
    float* EF   = bufB + (size_t)BS * 512;       // 32768x1027
    float* CRD  = EF   + (size_t)BS * 1027;      // 32768x2
    float* IMP  = CRD  + (size_t)BS * 2;         // 32768
    int*   IDX  = (int*)(IMP + BS);              // 8*512
    float* POS  = (float*)(IDX + 8 * 512);       // 8*512*2
    float* PROJ = POS + (size_t)8 * 512 * 2;     // 4096x512
    float* ST   = bufB;                          // reuse (df dead after h3)
    float* H4   = bufA;                          // reuse (h3 dead after ef)

    dim3 blk(256);
    // h1 = gelu(x@W1+b1) -> bufA
    gemm_f32<true, false><<<dim3(8, 512), blk, 0, stream>>>(
        x, 512, W1, 512, b1, bufA, 512, BS, 512, 512, nullptr, nullptr, 0);
    // df = gelu(h1@W2+b2) -> bufB
    gemm_f32<true, false><<<dim3(8, 512), blk, 0, stream>>>(
        bufA, 512, W2, 512, b2, bufB, 512, BS, 512, 512, nullptr, nullptr, 0);
    // coords
    coords_kernel<<<dim3(8192), blk, 0, stream>>>(bufB, Wc, bc, CRD);
    // h3 = gelu(df@We1[2:] + coords@We1[:2] + be1) -> bufA
    gemm_f32<true, true><<<dim3(8, 512), blk, 0, stream>>>(
        bufB, 512, We1 + 2 * 512, 512, be1, bufA, 512, BS, 512, 512,
        CRD, We1, 512);
    // ef = h3@We2+be2 -> EF (N=1027)
    gemm_f32<false, false><<<dim3(17, 512), blk, 0, stream>>>(
        bufA, 512, We2, 1027, be2, EF, 1027, BS, 1027, 512, nullptr, nullptr, 0);
    // importance
    importance_kernel<<<dim3(8192), blk, 0, stream>>>(EF, IMP);
    // top-512 per batch
    topk_kernel<<<dim3(8), dim3(1024), 0, stream>>>(IMP, IDX);
    // gather positions / states
    gather_kernel<<<dim3(4096), blk, 0, stream>>>(EF, IDX, POS, ST);
    // h4 = gelu(states@Wo1+bo1) -> H4
    gemm_f32<true, false><<<dim3(32, 64), blk, 0, stream>>>(
        ST, 1024, Wo1, 2048, bo1, H4, 2048, 4096, 2048, 1024, nullptr, nullptr, 0);
    // proj = h4@Wo2+bo2 -> PROJ
    gemm_f32<false, false><<<dim3(8, 64), blk, 0, stream>>>(
        H4, 2048, Wo2, 512, bo2, PROJ, 512, 4096, 512, 2048, nullptr, nullptr, 0);
    // fused attention output
    attn_out_kernel<<<dim3(157, 4, 8), blk, 0, stream>>>(POS, PROJ, out);
}

// Round 2
// 1720.638 us; speedup vs baseline: 1.5922x; 1.5922x over previous
//
#include <hip/hip_runtime.h>
#include <hip/hip_bf16.h>
#include <math.h>

// ---------------------------------------------------------------------------
// DFNPureModel round 2:
//   Pre-selection path (h1, df, coords, h3, ef, importance, topk) stays fp32
//   (selection must match reference top-k exactly).
//   Post-selection path (h4, proj, attn-out) moves to bf16 MFMA:
//     - states/H4/proj stored bf16; Wo1/Wo2 transposed+converted to [N][K] bf16
//     - gemm_bf16_mfma: 128x128 tile, 4 waves, 16x16x32 MFMA, global_load_lds
//     - attn_mfma: w=exp(-10 d^2) generated per-lane in A-fragment layout,
//       projT bf16 staged to LDS, fp32 accum, normalize by sum of bf16 w.
// ---------------------------------------------------------------------------

#define BM 64
#define BN 64
#define BK 16

typedef __attribute__((ext_vector_type(8))) short bf16x8;
typedef __attribute__((ext_vector_type(4))) float f32x4;

__device__ __forceinline__ float gelu_exact(float x) {
    return 0.5f * x * (1.0f + erff(x * 0.7071067811865476f));
}

__device__ __forceinline__ void async_copy16(const void* g, void* l) {
    __builtin_amdgcn_global_load_lds(
        (const __attribute__((address_space(1))) unsigned int*)g,
        (__attribute__((address_space(3))) unsigned int*)l, 16, 0, 0);
}

__device__ __forceinline__ short f32_to_bf16_bits(float f) {
    __hip_bfloat16 h = __float2bfloat16(f);
    union { __hip_bfloat16 h; short s; } u; u.h = h;
    return u.s;
}

// ===================== fp32 GEMM (pre-selection, unchanged) =================
template<bool GELU, bool RANK2>
__global__ __launch_bounds__(256) void gemm_f32(
    const float* __restrict__ A, int lda,
    const float* __restrict__ W, int ldw,
    const float* __restrict__ bias,
    float* __restrict__ C, int ldc,
    int M, int N, int K,
    const float* __restrict__ A2, const float* __restrict__ W2r, int ldw2)
{
    __shared__ float As[BK][BM + 4];
    __shared__ float Bs[BK][BN];
    const int rowStart = blockIdx.y * BM;
    const int colStart = blockIdx.x * BN;
    const int t  = threadIdx.x;
    const int ty = t >> 4, tx = t & 15;
    const int arow = t >> 2, acol = (t & 3) * 4;
    const int brow = t >> 4, bcol = (t & 15) * 4;
    float acc[4][4] = {};

    for (int k0 = 0; k0 < K; k0 += BK) {
        const float* ap = A + (size_t)(rowStart + arow) * lda + (k0 + acol);
        float4 av = *(const float4*)ap;
        As[acol + 0][arow] = av.x;
        As[acol + 1][arow] = av.y;
        As[acol + 2][arow] = av.z;
        As[acol + 3][arow] = av.w;
        const int c = colStart + bcol;
        const float* wp = W + (size_t)(k0 + brow) * ldw + c;
        float4 bv;
        if (c + 3 < N) {
            if ((((uintptr_t)wp) & 15) == 0) {
                bv = *(const float4*)wp;
            } else {
                bv.x = wp[0]; bv.y = wp[1]; bv.z = wp[2]; bv.w = wp[3];
            }
        } else {
            bv.x = (c + 0 < N) ? wp[0] : 0.f;
            bv.y = (c + 1 < N) ? wp[1] : 0.f;
            bv.z = (c + 2 < N) ? wp[2] : 0.f;
            bv.w = (c + 3 < N) ? wp[3] : 0.f;
        }
        Bs[brow][bcol + 0] = bv.x;
        Bs[brow][bcol + 1] = bv.y;
        Bs[brow][bcol + 2] = bv.z;
        Bs[brow][bcol + 3] = bv.w;
        __syncthreads();
        #pragma unroll
        for (int k = 0; k < BK; k++) {
            float4 a = *(const float4*)&As[k][ty * 4];
            float4 b = *(const float4*)&Bs[k][tx * 4];
            float ar[4] = {a.x, a.y, a.z, a.w};
            float br[4] = {b.x, b.y, b.z, b.w};
            #pragma unroll
            for (int i = 0; i < 4; i++)
                #pragma unroll
                for (int j = 0; j < 4; j++)
                    acc[i][j] += ar[i] * br[j];
        }
        __syncthreads();
    }
    #pragma unroll
    for (int i = 0; i < 4; i++) {
        const int row = rowStart + ty * 4 + i;
        float a20 = 0.f, a21 = 0.f;
        if (RANK2) { a20 = A2[(size_t)row * 2]; a21 = A2[(size_t)row * 2 + 1]; }
        #pragma unroll
        for (int j = 0; j < 4; j++) {
            const int col = colStart + tx * 4 + j;
            if (col < N) {
                float v = acc[i][j] + bias[col];
                if (RANK2) v += a20 * W2r[col] + a21 * W2r[ldw2 + col];
                if (GELU) v = gelu_exact(v);
                C[(size_t)row * ldc + col] = v;
            }
        }
    }
}

// ===================== small pre-selection kernels (unchanged) ==============
__global__ __launch_bounds__(256) void coords_kernel(
    const float* __restrict__ DF, const float* __restrict__ Wc,
    const float* __restrict__ bc, float* __restrict__ CRD)
{
    const int gid  = blockIdx.x * 256 + threadIdx.x;
    const int row  = gid >> 6;
    const int lane = gid & 63;
    const float* d = DF + (size_t)row * 512;
    float s0 = 0.f, s1 = 0.f;
    for (int k = lane; k < 512; k += 64) {
        const float v = d[k];
        const float2 wc = ((const float2*)Wc)[k];
        s0 += v * wc.x;
        s1 += v * wc.y;
    }
    #pragma unroll
    for (int off = 32; off; off >>= 1) {
        s0 += __shfl_down(s0, off);
        s1 += __shfl_down(s1, off);
    }
    if (lane == 0) {
        CRD[(size_t)row * 2 + 0] = s0 + bc[0];
        CRD[(size_t)row * 2 + 1] = s1 + bc[1];
    }
}

__global__ __launch_bounds__(256) void importance_kernel(
    const float* __restrict__ EF, float* __restrict__ IMP)
{
    const int gid  = blockIdx.x * 256 + threadIdx.x;
    const int row  = gid >> 6;
    const int lane = gid & 63;
    const float* e = EF + (size_t)row * 1027;
    float ss = 0.f;
    for (int k = lane; k < 1027; k += 64) { const float v = e[k]; ss += v * v; }
    #pragma unroll
    for (int off = 32; off; off >>= 1) ss += __shfl_down(ss, off);
    if (lane == 0) IMP[row] = sqrtf(ss);
}

__global__ __launch_bounds__(1024) void topk_kernel(
    const float* __restrict__ IMP, int* __restrict__ IDX)
{
    __shared__ float v[4096];
    __shared__ int   ix[4096];
    const int b = blockIdx.x, t = threadIdx.x;
    for (int i = t; i < 4096; i += 1024) { v[i] = IMP[b * 4096 + i]; ix[i] = i; }
    __syncthreads();
    for (int k = 2; k <= 4096; k <<= 1) {
        for (int j = k >> 1; j > 0; j >>= 1) {
            for (int q = 0; q < 4; q++) {
                const int i = t + (q << 10);
                const int l = i ^ j;
                if (l > i) {
                    const float vi = v[i], vl = v[l];
                    const int   ii = ix[i], il = ix[l];
                    const bool after = (vi < vl) || (vi == vl && ii > il);
                    const bool dirAsc = ((i & k) == 0);
                    if (dirAsc ? after : !after) {
                        v[i] = vl; v[l] = vi; ix[i] = il; ix[l] = ii;
                    }
                }
            }
            __syncthreads();
        }
    }
    if (t < 512) IDX[b * 512 + t] = ix[t];
}

// gather: positions fp32, states -> bf16
__global__ __launch_bounds__(256) void gather_kernel(
    const float* __restrict__ EF, const int* __restrict__ IDX,
    float* __restrict__ POS, __hip_bfloat16* __restrict__ ST)
{
    const int bn  = blockIdx.x;
    const int b   = bn >> 9;
    const int row = IDX[bn];
    const float* src = EF + ((size_t)(b * 4096) + row) * 1027;
    const int t = threadIdx.x;
    if (t < 2) POS[(size_t)bn * 2 + t] = src[t];
    __hip_bfloat16* dst = ST + (size_t)bn * 1024;
    for (int k = t; k < 1024; k += 256) dst[k] = __float2bfloat16(src[2 + k]);
}

// ===================== weight transpose + fp32->bf16 ========================
// in: W [K][N] fp32 ; out: WT [N][K] bf16. grid (N/32, K/32), 256 thr.
__global__ __launch_bounds__(256) void transpose_cvt_kernel(
    const float* __restrict__ in, __hip_bfloat16* __restrict__ out,
    int K, int N)
{
    __shared__ float tile[32][33];
    const int k0 = blockIdx.y * 32, n0 = blockIdx.x * 32;
    const int t = threadIdx.x;
    const int lr = t >> 5, lc = t & 31;
    #pragma unroll
    for (int p = 0; p < 4; p++) {
        const int r = p * 8 + lr;
        tile[r][lc] = in[(size_t)(k0 + r) * N + n0 + lc];
    }
    __syncthreads();
    #pragma unroll
    for (int p = 0; p < 4; p++) {
        const int r = p * 8 + lr;
        out[(size_t)(n0 + r) * K + k0 + lc] = __float2bfloat16(tile[lc][r]);
    }
}

// PROJ [b*512+n][512 d] bf16 -> PROJT [b][512 d][512 n] bf16. grid(16,16,8).
__global__ __launch_bounds__(256) void transpose_proj_kernel(
    const __hip_bfloat16* __restrict__ in, __hip_bfloat16* __restrict__ out)
{
    __shared__ __hip_bfloat16 tile[32][33];
    const int b = blockIdx.z;
    const int n0 = blockIdx.y * 32, d0 = blockIdx.x * 32;
    const int t = threadIdx.x;
    const int lr = t >> 5, lc = t & 31;
    #pragma unroll
    for (int p = 0; p < 4; p++) {
        const int r = p * 8 + lr;
        tile[r][lc] = in[((size_t)b * 512 + n0 + r) * 512 + d0 + lc];
    }
    __syncthreads();
    #pragma unroll
    for (int p = 0; p < 4; p++) {
        const int r = p * 8 + lr;
        out[((size_t)b * 512 + d0 + r) * 512 + n0 + lc] = tile[lc][r];
    }
}

// ===================== bf16 MFMA GEMM (post-selection) ======================
// C[M][N] = act(A[M][K] @ BT[N][K]^T + bias). All dims multiples of 128/32.
// 128x128 tile, 256 thr = 4 waves in 2x2, each wave 64x64 = 4x4 MFMA frags.
template<bool GELU>
__global__ __launch_bounds__(256) void gemm_bf16_mfma(
    const __hip_bfloat16* __restrict__ A,
    const __hip_bfloat16* __restrict__ BT,
    const float* __restrict__ bias,
    __hip_bfloat16* __restrict__ C,
    int M, int N, int K)
{
    __shared__ __align__(16) __hip_bfloat16 As[128][32];
    __shared__ __align__(16) __hip_bfloat16 Bs[128][32];
    const int t = threadIdx.x;
    const int wave = t >> 6, lane = t & 63;
    const int wave_m = wave >> 1, wave_n = wave & 1;
    const int fr = lane & 15, quad = lane >> 4;
    const int m0 = blockIdx.y * 128;
    const int n0 = blockIdx.x * 128;
    const int srow = lane >> 2;           // staging row within 16-row segment
    const int skc  = (lane & 3) * 8;      // staging k offset (8 bf16 = 16B)

    f32x4 acc[4][4] = {};

    for (int k0 = 0; k0 < K; k0 += 32) {
        #pragma unroll
        for (int s = 0; s < 2; s++) {
            const int seg = wave * 2 + s;
            const int row = seg * 16 + srow;
            async_copy16(A + (size_t)(m0 + row) * K + k0 + skc, &As[seg * 16][0]);
            async_copy16(BT + (size_t)(n0 + row) * K + k0 + skc, &Bs[seg * 16][0]);
        }
        __syncthreads();
        bf16x8 af[4], bfv[4];
        #pragma unroll
        for (int i = 0; i < 4; i++)
            af[i] = *(const bf16x8*)&As[wave_m * 64 + i * 16 + fr][quad * 8];
        #pragma unroll
        for (int j = 0; j < 4; j++)
            bfv[j] = *(const bf16x8*)&Bs[wave_n * 64 + j * 16 + fr][quad * 8];
        #pragma unroll
        for (int i = 0; i < 4; i++)
            #pragma unroll
            for (int j = 0; j < 4; j++)
                acc[i][j] = __builtin_amdgcn_mfma_f32_16x16x32_bf16(
                    af[i], bfv[j], acc[i][j], 0, 0, 0);
        __syncthreads();
    }
    // epilogue: C row = quad*4+reg, col = fr within each 16x16
    #pragma unroll
    for (int i = 0; i < 4; i++) {
        const int gm = m0 + wave_m * 64 + i * 16 + quad * 4;
        #pragma unroll
        for (int j = 0; j < 4; j++) {
            const int gn = n0 + wave_n * 64 + j * 16 + fr;
            const float bv = bias[gn];
            #pragma unroll
            for (int r = 0; r < 4; r++) {
                float v = acc[i][j][r] + bv;
                if (GELU) v = gelu_exact(v);
                C[(size_t)(gm + r) * N + gn] = __float2bfloat16(v);
            }
        }
    }
}

// ===================== fused attention output (bf16 MFMA) ===================
// out[b,g,d] = (sum_n w(g,n) proj[n,d]) / (sum_n w(g,n) + 1e-8)
// block: 64 g x 256 d, 4 waves (wave = 16 g rows, 16 n-frags of 16 d).
// w generated per-lane directly in MFMA A-fragment layout.
__global__ __launch_bounds__(256) void attn_mfma_kernel(
    const float* __restrict__ POS,            // [8][512][2]
    const __hip_bfloat16* __restrict__ PROJT, // [8][512 d][512 n]
    float* __restrict__ OUT)                  // [8][10000][512]
{
    __shared__ __align__(16) __hip_bfloat16 Bs[256][32];
    __shared__ float2 pos_s[512];
    __shared__ float srow_s[4][16];
    const int t = threadIdx.x;
    const int wave = t >> 6, lane = t & 63;
    const int fr = lane & 15, quad = lane >> 4;
    const int b  = blockIdx.z;
    const int g0 = blockIdx.x * 64;
    const int d0 = blockIdx.y * 256;

    { // stage all 512 positions of this batch
        const float2* p = (const float2*)(POS + (size_t)b * 512 * 2);
        pos_s[t]       = p[t];
        pos_s[256 + t] = p[256 + t];
    }
    const int g = g0 + wave * 16 + fr;     // my A-row (g point)
    const bool gv = g < 10000;
    const float step = 2.0f / 99.0f;
    const int gi = gv ? (g / 100) : 0;
    const int gj = gv ? (g - gi * 100) : 0;
    const float gx = -1.f + step * (float)gi;
    const float gy = -1.f + step * (float)gj;

    f32x4 acc[16] = {};
    float wsum = 0.f;
    __syncthreads();   // pos_s ready

    for (int n0 = 0; n0 < 512; n0 += 32) {
        // stage projT tile: 256 d-rows x 32 n (bf16) via global_load_lds
        #pragma unroll
        for (int s = 0; s < 4; s++) {
            const int seg = wave * 4 + s;
            const __hip_bfloat16* gB = PROJT
                + ((size_t)b * 512 + d0 + seg * 16 + (lane >> 2)) * 512
                + n0 + (lane & 3) * 8;
            async_copy16(gB, &Bs[seg * 16][0]);
        }
        // generate my w fragment (A-layout: m=fr, k=quad*8+j) while loads fly
        bf16x8 wf;
        float wl = 0.f;
        #pragma unroll
        for (int j = 0; j < 8; j++) {
            const int n = n0 + quad * 8 + j;
            const float2 pn = pos_s[n];
            const float dx = gx - pn.x, dy = gy - pn.y;
            const float w = gv ? __expf(-10.0f * (dx * dx + dy * dy)) : 0.f;
            const short wb = f32_to_bf16_bits(w);
            wf[j] = wb;
            union { short s; __hip_bfloat16 h; } u; u.s = wb;
            wl += __bfloat162float(u.h);
        }
        wsum += wl;
        __syncthreads();   // Bs ready
        #pragma unroll
        for (int j = 0; j < 16; j++) {
            const bf16x8 bv = *(const bf16x8*)&Bs[j * 16 + fr][quad * 8];
            acc[j] = __builtin_amdgcn_mfma_f32_16x16x32_bf16(wf, bv, acc[j], 0, 0, 0);
        }
        __syncthreads();
    }
    // wsum: reduce across quads (lanes sharing fr)
    wsum += __shfl_xor(wsum, 16);
    wsum += __shfl_xor(wsum, 32);
    if (lane < 16) srow_s[wave][lane] = wsum;
    __syncthreads();
    const int rbase = quad * 4;
    float inv[4];
    #pragma unroll
    for (int r = 0; r < 4; r++)
        inv[r] = 1.0f / (srow_s[wave][rbase + r] + 1e-8f);
    #pragma unroll
    for (int j = 0; j < 16; j++) {
        const int col = d0 + j * 16 + fr;
        #pragma unroll
        for (int r = 0; r < 4; r++) {
            const int gr = g0 + wave * 16 + rbase + r;
            if (gr < 10000)
                OUT[((size_t)b * 10000 + gr) * 512 + col] = acc[j][r] * inv[r];
        }
    }
}

// ===========================================================================
extern "C" void kernel_launch(void* const* d_in, const int* in_sizes, int n_in,
                              void* d_out, int out_size, void* d_ws, size_t ws_size,
                              hipStream_t stream)
{
    const float* x   = (const float*)d_in[0];
    const float* W1  = (const float*)d_in[1];
    const float* b1  = (const float*)d_in[2];
    const float* W2  = (const float*)d_in[3];
    const float* b2  = (const float*)d_in[4];
    const float* Wc  = (const float*)d_in[5];
    const float* bc  = (const float*)d_in[6];
    const float* We1 = (const float*)d_in[7];
    const float* be1 = (const float*)d_in[8];
    const float* We2 = (const float*)d_in[9];
    const float* be2 = (const float*)d_in[10];
    const float* Wo1 = (const float*)d_in[11];
    const float* bo1 = (const float*)d_in[12];
    const float* Wo2 = (const float*)d_in[13];
    const float* bo2 = (const float*)d_in[14];
    float* out = (float*)d_out;

    const int BS = 32768;
    // fp32 region
    float* bufA = (float*)d_ws;                  // 32768x512 (h1, then h3)
    float* bufB = bufA + (size_t)BS * 512;       // 32768x512 (df)
    float* EF   = bufB + (size_t)BS * 512;       // 32768x1027
    float* CRD  = EF   + (size_t)BS * 1027;      // 32768x2
    float* IMP  = CRD  + (size_t)BS * 2;         // 32768
    int*   IDX  = (int*)(IMP + BS);              // 8*512
    float* POS  = (float*)(IDX + 8 * 512);       // 8*512*2
    // bf16 pool aliased over bufA (h3 dead after the ef GEMM)
    __hip_bfloat16* pool  = (__hip_bfloat16*)bufA;
    __hip_bfloat16* ST    = pool;                    // 4096x1024
    __hip_bfloat16* H4    = ST    + (size_t)4096 * 1024;  // 4096x2048
    __hip_bfloat16* PROJ  = H4    + (size_t)4096 * 2048;  // 4096x512
    __hip_bfloat16* PROJT = PROJ  + (size_t)4096 * 512;   // 8x512x512
    __hip_bfloat16* Wo1T  = PROJT + (size_t)4096 * 512;   // 2048x1024
    __hip_bfloat16* Wo2T  = Wo1T  + (size_t)2048 * 1024;  // 512x2048

    dim3 blk(256);
    // ---- pre-selection (fp32) ----
    gemm_f32<true, false><<<dim3(8, 512), blk, 0, stream>>>(
        x, 512, W1, 512, b1, bufA, 512, BS, 512, 512, nullptr, nullptr, 0);
    gemm_f32<true, false><<<dim3(8, 512), blk, 0, stream>>>(
        bufA, 512, W2, 512, b2, bufB, 512, BS, 512, 512, nullptr, nullptr, 0);
    coords_kernel<<<dim3(8192), blk, 0, stream>>>(bufB, Wc, bc, CRD);
    gemm_f32<true, true><<<dim3(8, 512), blk, 0, stream>>>(
        bufB, 512, We1 + 2 * 512, 512, be1, bufA, 512, BS, 512, 512,
        CRD, We1, 512);
    gemm_f32<false, false><<<dim3(17, 512), blk, 0, stream>>>(
        bufA, 512, We2, 1027, be2, EF, 1027, BS, 1027, 512, nullptr, nullptr, 0);
    importance_kernel<<<dim3(8192), blk, 0, stream>>>(EF, IMP);
    topk_kernel<<<dim3(8), dim3(1024), 0, stream>>>(IMP, IDX);
    // ---- weight prep (bufA free from here) ----
    transpose_cvt_kernel<<<dim3(64, 32), blk, 0, stream>>>(Wo1, Wo1T, 1024, 2048);
    transpose_cvt_kernel<<<dim3(16, 64), blk, 0, stream>>>(Wo2, Wo2T, 2048, 512);
    // ---- selection gather (bf16 states) ----
    gather_kernel<<<dim3(4096), blk, 0, stream>>>(EF, IDX, POS, ST);
    // ---- post-selection (bf16 MFMA) ----
    gemm_bf16_mfma<true><<<dim3(16, 32), blk, 0, stream>>>(
        ST, Wo1T, bo1, H4, 4096, 2048, 1024);
    gemm_bf16_mfma<false><<<dim3(4, 32), blk, 0, stream>>>(
        H4, Wo2T, bo2, PROJ, 4096, 512, 2048);
    transpose_proj_kernel<<<dim3(16, 16, 8), blk, 0, stream>>>(PROJ, PROJT);
    attn_mfma_kernel<<<dim3(157, 2, 8), blk, 0, stream>>>(POS, PROJT, out);
}

// Round 3
// 915.948 us; speedup vs baseline: 2.9910x; 1.8785x over previous
//
#include <hip/hip_runtime.h>
#include <hip/hip_bf16.h>
#include <math.h>

// ---------------------------------------------------------------------------
// DFNPureModel round 3:
//   Pre-selection GEMMs (h1, df, h3, ef) -> bf16x3 split MFMA emulation:
//     a = hi + lo (bf16 pair), a*b ~= hi*hi + hi*lo + lo*hi, fp32 accumulate.
//     ~17 mantissa bits effective -> importance error ~1e-5 rel, preserves
//     the reference top-k set (verified by absmax staying at 1 quantum).
//   Activations stored as bf16 hi/lo pairs between GEMMs; weights pre-split
//   and transposed to [N][K]. ef stored fp32 (importance + gather need it).
//   Post-selection path (h4, proj, attn) unchanged from round 2 (bf16 MFMA).
// ---------------------------------------------------------------------------

typedef __attribute__((ext_vector_type(8))) short bf16x8;
typedef __attribute__((ext_vector_type(4))) float f32x4;

__device__ __forceinline__ float gelu_exact(float x) {
    return 0.5f * x * (1.0f + erff(x * 0.7071067811865476f));
}

__device__ __forceinline__ void async_copy16(const void* g, void* l) {
    __builtin_amdgcn_global_load_lds(
        (const __attribute__((address_space(1))) unsigned int*)g,
        (__attribute__((address_space(3))) unsigned int*)l, 16, 0, 0);
}

__device__ __forceinline__ float bf16bits_to_f(short s) {
    union { short s; __hip_bfloat16 h; } u; u.s = s;
    return __bfloat162float(u.h);
}

// ===================== elementwise fp32 -> (hi, lo) bf16 split ==============
__global__ __launch_bounds__(256) void split_kernel(
    const float* __restrict__ in,
    __hip_bfloat16* __restrict__ hi, __hip_bfloat16* __restrict__ lo)
{
    const int i4 = blockIdx.x * 256 + threadIdx.x;
    const float4 v = ((const float4*)in)[i4];
    __hip_bfloat16 h0 = __float2bfloat16(v.x);
    __hip_bfloat16 h1 = __float2bfloat16(v.y);
    __hip_bfloat16 h2 = __float2bfloat16(v.z);
    __hip_bfloat16 h3 = __float2bfloat16(v.w);
    __hip_bfloat16 l0 = __float2bfloat16(v.x - __bfloat162float(h0));
    __hip_bfloat16 l1 = __float2bfloat16(v.y - __bfloat162float(h1));
    __hip_bfloat16 l2 = __float2bfloat16(v.z - __bfloat162float(h2));
    __hip_bfloat16 l3 = __float2bfloat16(v.w - __bfloat162float(h3));
    union { __hip_bfloat16 h[4]; short4 s; } uh, ul;
    uh.h[0] = h0; uh.h[1] = h1; uh.h[2] = h2; uh.h[3] = h3;
    ul.h[0] = l0; ul.h[1] = l1; ul.h[2] = l2; ul.h[3] = l3;
    ((short4*)hi)[i4] = uh.s;
    ((short4*)lo)[i4] = ul.s;
}

// ============ W [K][N] fp32 -> WT hi/lo [Npad][K] bf16 (zero-padded) ========
__global__ __launch_bounds__(256) void transpose_split_kernel(
    const float* __restrict__ in,
    __hip_bfloat16* __restrict__ outH, __hip_bfloat16* __restrict__ outL,
    int K, int N)
{
    __shared__ float tile[32][33];
    const int k0 = blockIdx.y * 32, n0 = blockIdx.x * 32;
    const int t = threadIdx.x;
    const int lr = t >> 5, lc = t & 31;
    #pragma unroll
    for (int p = 0; p < 4; p++) {
        const int r = p * 8 + lr;
        const int n = n0 + lc;
        tile[r][lc] = (n < N) ? in[(size_t)(k0 + r) * N + n] : 0.f;
    }
    __syncthreads();
    #pragma unroll
    for (int p = 0; p < 4; p++) {
        const int r = p * 8 + lr;
        const float v = tile[lc][r];
        const __hip_bfloat16 h = __float2bfloat16(v);
        const __hip_bfloat16 l = __float2bfloat16(v - __bfloat162float(h));
        outH[(size_t)(n0 + r) * K + k0 + lc] = h;
        outL[(size_t)(n0 + r) * K + k0 + lc] = l;
    }
}

// ===================== bf16x3 split-MFMA GEMM (pre-selection) ===============
// C = act(A @ BT^T + bias [+ rank2]) with A = Ahi+Alo [M][K], BT = Bhi+Blo
// [Npad][K].  128x128x32 tile, 4 waves 2x2, 16x16x32 MFMA, 3 MFMA per frag.
// SPLIT: C written as bf16 hi/lo pair.  !SPLIT: C written fp32 (ldc, bounds).
template<bool GELU, bool RANK2, bool SPLIT, bool BOUNDS>
__global__ __launch_bounds__(256) void gemm_bf16x3(
    const __hip_bfloat16* __restrict__ Ahi, const __hip_bfloat16* __restrict__ Alo,
    const __hip_bfloat16* __restrict__ Bhi, const __hip_bfloat16* __restrict__ Blo,
    const float* __restrict__ bias,
    float* __restrict__ Cf, int ldc,
    __hip_bfloat16* __restrict__ Chi, __hip_bfloat16* __restrict__ Clo,
    int N, int K,
    const float* __restrict__ A2, const float* __restrict__ W2r)
{
    __shared__ __align__(16) __hip_bfloat16 AsH[128][32];
    __shared__ __align__(16) __hip_bfloat16 AsL[128][32];
    __shared__ __align__(16) __hip_bfloat16 BsH[128][32];
    __shared__ __align__(16) __hip_bfloat16 BsL[128][32];
    const int t = threadIdx.x;
    const int wave = t >> 6, lane = t & 63;
    const int wave_m = wave >> 1, wave_n = wave & 1;
    const int fr = lane & 15, quad = lane >> 4;
    const int m0 = blockIdx.y * 128;
    const int n0 = blockIdx.x * 128;
    const int srow = lane >> 2;
    const int skc  = (lane & 3) * 8;

    f32x4 acc[4][4] = {};

    for (int k0 = 0; k0 < K; k0 += 32) {
        #pragma unroll
        for (int s = 0; s < 2; s++) {
            const int seg = wave * 2 + s;
            const int row = seg * 16 + srow;
            const size_t ao = (size_t)(m0 + row) * K + k0 + skc;
            const size_t bo = (size_t)(n0 + row) * K + k0 + skc;
            async_copy16(Ahi + ao, &AsH[seg * 16][0]);
            async_copy16(Alo + ao, &AsL[seg * 16][0]);
            async_copy16(Bhi + bo, &BsH[seg * 16][0]);
            async_copy16(Blo + bo, &BsL[seg * 16][0]);
        }
        __syncthreads();
        bf16x8 ah[4], al[4], bh[4], bl[4];
        #pragma unroll
        for (int i = 0; i < 4; i++) {
            ah[i] = *(const bf16x8*)&AsH[wave_m * 64 + i * 16 + fr][quad * 8];
            al[i] = *(const bf16x8*)&AsL[wave_m * 64 + i * 16 + fr][quad * 8];
        }
        #pragma unroll
        for (int j = 0; j < 4; j++) {
            bh[j] = *(const bf16x8*)&BsH[wave_n * 64 + j * 16 + fr][quad * 8];
            bl[j] = *(const bf16x8*)&BsL[wave_n * 64 + j * 16 + fr][quad * 8];
        }
        #pragma unroll
        for (int i = 0; i < 4; i++)
            #pragma unroll
            for (int j = 0; j < 4; j++) {
                acc[i][j] = __builtin_amdgcn_mfma_f32_16x16x32_bf16(
                    ah[i], bh[j], acc[i][j], 0, 0, 0);
                acc[i][j] = __builtin_amdgcn_mfma_f32_16x16x32_bf16(
                    ah[i], bl[j], acc[i][j], 0, 0, 0);
                acc[i][j] = __builtin_amdgcn_mfma_f32_16x16x32_bf16(
                    al[i], bh[j], acc[i][j], 0, 0, 0);
            }
        __syncthreads();
    }
    // epilogue: row = m0 + wave_m*64 + i*16 + quad*4 + r, col = n0 + wave_n*64
    // + j*16 + fr
    #pragma unroll
    for (int i = 0; i < 4; i++) {
        const int gmb = m0 + wave_m * 64 + i * 16 + quad * 4;
        #pragma unroll
        for (int j = 0; j < 4; j++) {
            const int gn = n0 + wave_n * 64 + j * 16 + fr;
            const bool nok = !BOUNDS || (gn < N);
            const float bv = nok ? bias[gn] : 0.f;
            float w2a = 0.f, w2b = 0.f;
            if (RANK2) { w2a = W2r[gn]; w2b = W2r[512 + gn]; }
            #pragma unroll
            for (int r = 0; r < 4; r++) {
                const int gm = gmb + r;
                float v = acc[i][j][r] + bv;
                if (RANK2)
                    v += A2[(size_t)gm * 2] * w2a + A2[(size_t)gm * 2 + 1] * w2b;
                if (GELU) v = gelu_exact(v);
                if (SPLIT) {
                    const __hip_bfloat16 h = __float2bfloat16(v);
                    const __hip_bfloat16 l =
                        __float2bfloat16(v - __bfloat162float(h));
                    Chi[(size_t)gm * 512 + gn] = h;
                    Clo[(size_t)gm * 512 + gn] = l;
                } else if (nok) {
                    Cf[(size_t)gm * ldc + gn] = v;
                }
            }
        }
    }
}

// ===================== small pre-selection kernels ==========================
// coords = df@Wc + bc : one wave per row, df from hi/lo pair
__global__ __launch_bounds__(256) void coords_kernel(
    const __hip_bfloat16* __restrict__ DFh, const __hip_bfloat16* __restrict__ DFl,
    const float* __restrict__ Wc,
    const float* __restrict__ bc, float* __restrict__ CRD)
{
    const int gid  = blockIdx.x * 256 + threadIdx.x;
    const int row  = gid >> 6;
    const int lane = gid & 63;
    const __hip_bfloat16* dh = DFh + (size_t)row * 512;
    const __hip_bfloat16* dl = DFl + (size_t)row * 512;
    float s0 = 0.f, s1 = 0.f;
    for (int k = lane; k < 512; k += 64) {
        const float v = __bfloat162float(dh[k]) + __bfloat162float(dl[k]);
        const float2 wc = ((const float2*)Wc)[k];
        s0 += v * wc.x;
        s1 += v * wc.y;
    }
    #pragma unroll
    for (int off = 32; off; off >>= 1) {
        s0 += __shfl_down(s0, off);
        s1 += __shfl_down(s1, off);
    }
    if (lane == 0) {
        CRD[(size_t)row * 2 + 0] = s0 + bc[0];
        CRD[(size_t)row * 2 + 1] = s1 + bc[1];
    }
}

__global__ __launch_bounds__(256) void importance_kernel(
    const float* __restrict__ EF, float* __restrict__ IMP)
{
    const int gid  = blockIdx.x * 256 + threadIdx.x;
    const int row  = gid >> 6;
    const int lane = gid & 63;
    const float* e = EF + (size_t)row * 1027;
    float ss = 0.f;
    for (int k = lane; k < 1027; k += 64) { const float v = e[k]; ss += v * v; }
    #pragma unroll
    for (int off = 32; off; off >>= 1) ss += __shfl_down(ss, off);
    if (lane == 0) IMP[row] = sqrtf(ss);
}

__global__ __launch_bounds__(1024) void topk_kernel(
    const float* __restrict__ IMP, int* __restrict__ IDX)
{
    __shared__ float v[4096];
    __shared__ int   ix[4096];
    const int b = blockIdx.x, t = threadIdx.x;
    for (int i = t; i < 4096; i += 1024) { v[i] = IMP[b * 4096 + i]; ix[i] = i; }
    __syncthreads();
    for (int k = 2; k <= 4096; k <<= 1) {
        for (int j = k >> 1; j > 0; j >>= 1) {
            for (int q = 0; q < 4; q++) {
                const int i = t + (q << 10);
                const int l = i ^ j;
                if (l > i) {
                    const float vi = v[i], vl = v[l];
                    const int   ii = ix[i], il = ix[l];
                    const bool after = (vi < vl) || (vi == vl && ii > il);
                    const bool dirAsc = ((i & k) == 0);
                    if (dirAsc ? after : !after) {
                        v[i] = vl; v[l] = vi; ix[i] = il; ix[l] = ii;
                    }
                }
            }
            __syncthreads();
        }
    }
    if (t < 512) IDX[b * 512 + t] = ix[t];
}

__global__ __launch_bounds__(256) void gather_kernel(
    const float* __restrict__ EF, const int* __restrict__ IDX,
    float* __restrict__ POS, __hip_bfloat16* __restrict__ ST)
{
    const int bn  = blockIdx.x;
    const int b   = bn >> 9;
    const int row = IDX[bn];
    const float* src = EF + ((size_t)(b * 4096) + row) * 1027;
    const int t = threadIdx.x;
    if (t < 2) POS[(size_t)bn * 2 + t] = src[t];
    __hip_bfloat16* dst = ST + (size_t)bn * 1024;
    for (int k = t; k < 1024; k += 256) dst[k] = __float2bfloat16(src[2 + k]);
}

// ===================== weight transpose + fp32->bf16 (post-sel) =============
__global__ __launch_bounds__(256) void transpose_cvt_kernel(
    const float* __restrict__ in, __hip_bfloat16* __restrict__ out,
    int K, int N)
{
    __shared__ float tile[32][33];
    const int k0 = blockIdx.y * 32, n0 = blockIdx.x * 32;
    const int t = threadIdx.x;
    const int lr = t >> 5, lc = t & 31;
    #pragma unroll
    for (int p = 0; p < 4; p++) {
        const int r = p * 8 + lr;
        tile[r][lc] = in[(size_t)(k0 + r) * N + n0 + lc];
    }
    __syncthreads();
    #pragma unroll
    for (int p = 0; p < 4; p++) {
        const int r = p * 8 + lr;
        out[(size_t)(n0 + r) * K + k0 + lc] = __float2bfloat16(tile[lc][r]);
    }
}

__global__ __launch_bounds__(256) void transpose_proj_kernel(
    const __hip_bfloat16* __restrict__ in, __hip_bfloat16* __restrict__ out)
{
    __shared__ __hip_bfloat16 tile[32][33];
    const int b = blockIdx.z;
    const int n0 = blockIdx.y * 32, d0 = blockIdx.x * 32;
    const int t = threadIdx.x;
    const int lr = t >> 5, lc = t & 31;
    #pragma unroll
    for (int p = 0; p < 4; p++) {
        const int r = p * 8 + lr;
        tile[r][lc] = in[((size_t)b * 512 + n0 + r) * 512 + d0 + lc];
    }
    __syncthreads();
    #pragma unroll
    for (int p = 0; p < 4; p++) {
        const int r = p * 8 + lr;
        out[((size_t)b * 512 + d0 + r) * 512 + n0 + lc] = tile[lc][r];
    }
}

// ===================== bf16 MFMA GEMM (post-selection) ======================
template<bool GELU>
__global__ __launch_bounds__(256) void gemm_bf16_mfma(
    const __hip_bfloat16* __restrict__ A,
    const __hip_bfloat16* __restrict__ BT,
    const float* __restrict__ bias,
    __hip_bfloat16* __restrict__ C,
    int M, int N, int K)
{
    __shared__ __align__(16) __hip_bfloat16 As[128][32];
    __shared__ __align__(16) __hip_bfloat16 Bs[128][32];
    const int t = threadIdx.x;
    const int wave = t >> 6, lane = t & 63;
    const int wave_m = wave >> 1, wave_n = wave & 1;
    const int fr = lane & 15, quad = lane >> 4;
    const int m0 = blockIdx.y * 128;
    const int n0 = blockIdx.x * 128;
    const int srow = lane >> 2;
    const int skc  = (lane & 3) * 8;

    f32x4 acc[4][4] = {};

    for (int k0 = 0; k0 < K; k0 += 32) {
        #pragma unroll
        for (int s = 0; s < 2; s++) {
            const int seg = wave * 2 + s;
            const int row = seg * 16 + srow;
            async_copy16(A + (size_t)(m0 + row) * K + k0 + skc, &As[seg * 16][0]);
            async_copy16(BT + (size_t)(n0 + row) * K + k0 + skc, &Bs[seg * 16][0]);
        }
        __syncthreads();
        bf16x8 af[4], bfv[4];
        #pragma unroll
        for (int i = 0; i < 4; i++)
            af[i] = *(const bf16x8*)&As[wave_m * 64 + i * 16 + fr][quad * 8];
        #pragma unroll
        for (int j = 0; j < 4; j++)
            bfv[j] = *(const bf16x8*)&Bs[wave_n * 64 + j * 16 + fr][quad * 8];
        #pragma unroll
        for (int i = 0; i < 4; i++)
            #pragma unroll
            for (int j = 0; j < 4; j++)
                acc[i][j] = __builtin_amdgcn_mfma_f32_16x16x32_bf16(
                    af[i], bfv[j], acc[i][j], 0, 0, 0);
        __syncthreads();
    }
    #pragma unroll
    for (int i = 0; i < 4; i++) {
        const int gm = m0 + wave_m * 64 + i * 16 + quad * 4;
        #pragma unroll
        for (int j = 0; j < 4; j++) {
            const int gn = n0 + wave_n * 64 + j * 16 + fr;
            const float bv = bias[gn];
            #pragma unroll
            for (int r = 0; r < 4; r++) {
                float v = acc[i][j][r] + bv;
                if (GELU) v = gelu_exact(v);
                C[(size_t)(gm + r) * N + gn] = __float2bfloat16(v);
            }
        }
    }
}

// ===================== fused attention output (bf16 MFMA) ===================
__global__ __launch_bounds__(256) void attn_mfma_kernel(
    const float* __restrict__ POS,
    const __hip_bfloat16* __restrict__ PROJT,
    float* __restrict__ OUT)
{
    __shared__ __align__(16) __hip_bfloat16 Bs[256][32];
    __shared__ float2 pos_s[512];
    __shared__ float srow_s[4][16];
    const int t = threadIdx.x;
    const int wave = t >> 6, lane = t & 63;
    const int fr = lane & 15, quad = lane >> 4;
    const int b  = blockIdx.z;
    const int g0 = blockIdx.x * 64;
    const int d0 = blockIdx.y * 256;

    {
        const float2* p = (const float2*)(POS + (size_t)b * 512 * 2);
        pos_s[t]       = p[t];
        pos_s[256 + t] = p[256 + t];
    }
    const int g = g0 + wave * 16 + fr;
    const bool gv = g < 10000;
    const float step = 2.0f / 99.0f;
    const int gi = gv ? (g / 100) : 0;
    const int gj = gv ? (g - gi * 100) : 0;
    const float gx = -1.f + step * (float)gi;
    const float gy = -1.f + step * (float)gj;

    f32x4 acc[16] = {};
    float wsum = 0.f;
    __syncthreads();

    for (int n0 = 0; n0 < 512; n0 += 32) {
        #pragma unroll
        for (int s = 0; s < 4; s++) {
            const int seg = wave * 4 + s;
            const __hip_bfloat16* gB = PROJT
                + ((size_t)b * 512 + d0 + seg * 16 + (lane >> 2)) * 512
                + n0 + (lane & 3) * 8;
            async_copy16(gB, &Bs[seg * 16][0]);
        }
        bf16x8 wf;
        float wl = 0.f;
        #pragma unroll
        for (int j = 0; j < 8; j++) {
            const int n = n0 + quad * 8 + j;
            const float2 pn = pos_s[n];
            const float dx = gx - pn.x, dy = gy - pn.y;
            const float w = gv ? __expf(-10.0f * (dx * dx + dy * dy)) : 0.f;
            const __hip_bfloat16 wb = __float2bfloat16(w);
            union { __hip_bfloat16 h; short s; } u; u.h = wb;
            wf[j] = u.s;
            wl += __bfloat162float(wb);
        }
        wsum += wl;
        __syncthreads();
        #pragma unroll
        for (int j = 0; j < 16; j++) {
            const bf16x8 bv = *(const bf16x8*)&Bs[j * 16 + fr][quad * 8];
            acc[j] = __builtin_amdgcn_mfma_f32_16x16x32_bf16(wf, bv, acc[j], 0, 0, 0);
        }
        __syncthreads();
    }
    wsum += __shfl_xor(wsum, 16);
    wsum += __shfl_xor(wsum, 32);
    if (lane < 16) srow_s[wave][lane] = wsum;
    __syncthreads();
    const int rbase = quad * 4;
    float inv[4];
    #pragma unroll
    for (int r = 0; r < 4; r++)
        inv[r] = 1.0f / (srow_s[wave][rbase + r] + 1e-8f);
    #pragma unroll
    for (int j = 0; j < 16; j++) {
        const int col = d0 + j * 16 + fr;
        #pragma unroll
        for (int r = 0; r < 4; r++) {
            const int gr = g0 + wave * 16 + rbase + r;
            if (gr < 10000)
                OUT[((size_t)b * 10000 + gr) * 512 + col] = acc[j][r] * inv[r];
        }
    }
}

// ===========================================================================
extern "C" void kernel_launch(void* const* d_in, const int* in_sizes, int n_in,
                              void* d_out, int out_size, void* d_ws, size_t ws_size,
                              hipStream_t stream)
{
    const float* x   = (const float*)d_in[0];
    const float* W1  = (const float*)d_in[1];
    const float* b1  = (const float*)d_in[2];
    const float* W2  = (const float*)d_in[3];
    const float* b2  = (const float*)d_in[4];
    const float* Wc  = (const float*)d_in[5];
    const float* bc  = (const float*)d_in[6];
    const float* We1 = (const float*)d_in[7];
    const float* be1 = (const float*)d_in[8];
    const float* We2 = (const float*)d_in[9];
    const float* be2 = (const float*)d_in[10];
    const float* Wo1 = (const float*)d_in[11];
    const float* bo1 = (const float*)d_in[12];
    const float* Wo2 = (const float*)d_in[13];
    const float* bo2 = (const float*)d_in[14];
    float* out = (float*)d_out;

    const size_t BS = 32768;
    const size_t ACT = BS * 512;             // elements per activation matrix
    // ---- workspace layout ----
    __hip_bfloat16* P0h = (__hip_bfloat16*)d_ws;        // 32 MB
    __hip_bfloat16* P0l = P0h + ACT;                    // 32 MB
    __hip_bfloat16* P1h = P0l + ACT;                    // 32 MB
    __hip_bfloat16* P1l = P1h + ACT;                    // 32 MB
    float* EF  = (float*)(P1l + ACT);                   // 32768x1027 fp32
    float* CRD = EF + BS * 1027;                        // 32768x2
    float* IMP = CRD + BS * 2;                          // 32768
    int*   IDX = (int*)(IMP + BS);                      // 4096
    float* POS = (float*)(IDX + 4096);                  // 4096x2
    __hip_bfloat16* W1Th = (__hip_bfloat16*)(POS + 4096 * 2);   // 512x512
    __hip_bfloat16* W1Tl = W1Th + 512 * 512;
    __hip_bfloat16* W2Th = W1Tl + 512 * 512;
    __hip_bfloat16* W2Tl = W2Th + 512 * 512;
    __hip_bfloat16* We1Th = W2Tl + 512 * 512;
    __hip_bfloat16* We1Tl = We1Th + 512 * 512;
    __hip_bfloat16* We2Th = We1Tl + 512 * 512;          // 1152x512
    __hip_bfloat16* We2Tl = We2Th + (size_t)1152 * 512;
    // post-selection pool aliases P0 (dead after h3 GEMM)
    __hip_bfloat16* ST    = P0h;                           // 4096x1024
    __hip_bfloat16* H4    = ST + (size_t)4096 * 1024;      // 4096x2048
    __hip_bfloat16* PROJ  = H4 + (size_t)4096 * 2048;      // 4096x512
    __hip_bfloat16* PROJT = PROJ + (size_t)4096 * 512;     // 8x512x512
    __hip_bfloat16* Wo1T  = PROJT + (size_t)4096 * 512;    // 2048x1024
    __hip_bfloat16* Wo2T  = Wo1T + (size_t)2048 * 1024;    // 512x2048

    dim3 blk(256);
    // ---- prep: split x, split+transpose pre-selection weights ----
    split_kernel<<<dim3(16384), blk, 0, stream>>>(x, P0h, P0l);
    transpose_split_kernel<<<dim3(16, 16), blk, 0, stream>>>(W1, W1Th, W1Tl, 512, 512);
    transpose_split_kernel<<<dim3(16, 16), blk, 0, stream>>>(W2, W2Th, W2Tl, 512, 512);
    transpose_split_kernel<<<dim3(16, 16), blk, 0, stream>>>(We1 + 2 * 512, We1Th, We1Tl, 512, 512);
    transpose_split_kernel<<<dim3(36, 16), blk, 0, stream>>>(We2, We2Th, We2Tl, 512, 1027);
    // ---- pre-selection (bf16x3 MFMA) ----
    // h1 = gelu(x@W1+b1) -> P1 pair
    gemm_bf16x3<true, false, true, false><<<dim3(4, 256), blk, 0, stream>>>(
        P0h, P0l, W1Th, W1Tl, b1, nullptr, 0, P1h, P1l, 512, 512,
        nullptr, nullptr);
    // df = gelu(h1@W2+b2) -> P0 pair
    gemm_bf16x3<true, false, true, false><<<dim3(4, 256), blk, 0, stream>>>(
        P1h, P1l, W2Th, W2Tl, b2, nullptr, 0, P0h, P0l, 512, 512,
        nullptr, nullptr);
    // coords = df@Wc+bc
    coords_kernel<<<dim3(8192), blk, 0, stream>>>(P0h, P0l, Wc, bc, CRD);
    // h3 = gelu(df@We1[2:] + coords@We1[:2] + be1) -> P1 pair
    gemm_bf16x3<true, true, true, false><<<dim3(4, 256), blk, 0, stream>>>(
        P0h, P0l, We1Th, We1Tl, be1, nullptr, 0, P1h, P1l, 512, 512,
        CRD, We1);
    // ef = h3@We2+be2 -> EF fp32 (N=1027, padded BT)
    gemm_bf16x3<false, false, false, true><<<dim3(9, 256), blk, 0, stream>>>(
        P1h, P1l, We2Th, We2Tl, be2, EF, 1027, nullptr, nullptr, 1027, 512,
        nullptr, nullptr);
    // ---- selection ----
    importance_kernel<<<dim3(8192), blk, 0, stream>>>(EF, IMP);
    topk_kernel<<<dim3(8), dim3(1024), 0, stream>>>(IMP, IDX);
    // ---- post-selection weight prep (P0 pool free from here) ----
    transpose_cvt_kernel<<<dim3(64, 32), blk, 0, stream>>>(Wo1, Wo1T, 1024, 2048);
    transpose_cvt_kernel<<<dim3(16, 64), blk, 0, stream>>>(Wo2, Wo2T, 2048, 512);
    gather_kernel<<<dim3(4096), blk, 0, stream>>>(EF, IDX, POS, ST);
    // ---- post-selection (bf16 MFMA) ----
    gemm_bf16_mfma<true><<<dim3(16, 32), blk, 0, stream>>>(
        ST, Wo1T, bo1, H4, 4096, 2048, 1024);
    gemm_bf16_mfma<false><<<dim3(4, 32), blk, 0, stream>>>(
        H4, Wo2T, bo2, PROJ, 4096, 512, 2048);
    transpose_proj_kernel<<<dim3(16, 16, 8), blk, 0, stream>>>(PROJ, PROJT);
    attn_mfma_kernel<<<dim3(157, 2, 8), blk, 0, stream>>>(POS, PROJT, out);
}